// Round 12
// baseline (237.989 us; speedup 1.0000x reference)
//
#include <hip/hip_runtime.h>
#include <stdint.h>

#define N_BOX 8400
#define NCLS 80
#define PSTRIDE 85
#define NW 132            // 64-box blocks covering 8400
#define NTILE 8778        // NW*(NW+1)/2 upper-tri tiles
#define ZROWI N_BOX       // mask row 8400 = all zeros (dummy row target)
#define CONF_T 0.01f
#define NMS_T 0.2f

typedef unsigned long long u64;

// ws layout (bytes). diagT/sup1/sup2/sup3 ALIAS det+keys: both dead after
// rank_k; tiles written by mask_k (later in-stream) — lifetimes disjoint.
#define OFF_DET     0                    // 8400 x 8 f32   = 268800
#define OFF_DIAGT   0                    // 132*64 u64     = 67584  (alias)
#define OFF_SUP1    67584                // 132*64 u64     = 67584  (alias)
#define OFF_SUP2    135168               // 132*64 u64     = 67584  (alias)
#define OFF_SUP3    202752               // 132*64 u64     = 67584  (alias, spills into keys region — keys dead then)
#define OFF_KEYS    268800               // 8400 u32       = 33600
#define OFF_DETS    336000               // 8400 x 8 f32   = 268800
#define OFF_BOXESS  604800               // 8400 float4    = 134400
#define OFF_MASK    739200               // 8401 x 132 u64 = 8871456 (row 8400 = zeros)
#define OFF_KEEPW   9610656              // 132 u64        = 1056
#define OFF_VCNT    9611712              // 1 int

__device__ __forceinline__ unsigned fmap_desc(float f) {
    unsigned u = __float_as_uint(f);
    unsigned m = (u & 0x80000000u) ? ~u : (u | 0x80000000u); // monotone ascending
    return ~m;                                               // descending
}

__device__ __forceinline__ u64 shfl_xor64(u64 v, int m) {
    int lo = __shfl_xor((int)(unsigned)v, m);
    int hi = __shfl_xor((int)(unsigned)(v >> 32), m);
    return ((u64)(unsigned)hi << 32) | (unsigned)lo;
}

// 64x64 bit-matrix transpose across lanes. Verified R8-R11 (absmax 0).
__device__ __forceinline__ u64 bittranspose64(u64 x, int lane) {
    const u64 P0 = 0x5555555555555555ull, P1 = 0x3333333333333333ull,
              P2 = 0x0F0F0F0F0F0F0F0Full, P3 = 0x00FF00FF00FF00FFull,
              P4 = 0x0000FFFF0000FFFFull, P5 = 0x00000000FFFFFFFFull;
#define TSTEP(s, p) do {                                                 \
        u64 y = shfl_xor64(x, s);                                        \
        x = (lane & (s)) ? ((x & ~(p)) | ((y & ~(p)) >> (s)))            \
                         : ((x & (p))  | ((y & (p))  << (s)));           \
    } while (0)
    TSTEP(1, P0); TSTEP(2, P1); TSTEP(4, P2);
    TSTEP(8, P3); TSTEP(16, P4); TSTEP(32, P5);
#undef TSTEP
    return x;
}

__device__ __forceinline__ u64 wmask(int w, int V) {
    int nb = V - (w << 6);
    if (nb <= 0) return 0ull;
    if (nb >= 64) return ~0ull;
    return (1ull << nb) - 1ull;
}

// position of k-th set bit of v (k>=popcount -> garbage, caller clamps)
__device__ __forceinline__ int selbit(u64 v, int k) {
    int idx = 0;
    int c = __popcll(v & 0xFFFFFFFFull);
    if (k >= c) { k -= c; idx += 32; v >>= 32; }
    unsigned lo = (unsigned)v;
    c = __popc(lo & 0xFFFFu); if (k >= c) { k -= c; idx += 16; lo >>= 16; }
    c = __popc(lo & 0xFFu);   if (k >= c) { k -= c; idx += 8;  lo >>= 8;  }
    c = __popc(lo & 0xFu);    if (k >= c) { k -= c; idx += 4;  lo >>= 4;  }
    c = __popc(lo & 0x3u);    if (k >= c) { k -= c; idx += 2;  lo >>= 2;  }
    c = lo & 1u;              if (k >= c) { idx += 1; }
    return idx;
}

// Raw barrier: LDS drained, vmcnt pipeline PRESERVED (no __syncthreads drain).
__device__ __forceinline__ void step_barrier() {
    asm volatile("s_waitcnt lgkmcnt(0)" ::: "memory");
    __builtin_amdgcn_s_barrier();
    asm volatile("" ::: "memory");
}

__device__ __forceinline__ void gload16(const void* gsrc, void* lds_dst) {
    __builtin_amdgcn_global_load_lds(
        (const __attribute__((address_space(1))) void*)gsrc,
        (__attribute__((address_space(3))) void*)lds_dst, 16, 0, 0);
}

// ---- kernel A: per-row preprocess, 4 lanes per row; zeroes mask row 8400 ----
__global__ __launch_bounds__(256) void prep_k(const float* __restrict__ pred,
                                              float* __restrict__ det,
                                              unsigned* __restrict__ keys,
                                              u64* __restrict__ mask) {
    if (blockIdx.x == 0 && threadIdx.x < NW)
        mask[(size_t)ZROWI * NW + threadIdx.x] = 0ull;
    int gt = blockIdx.x * 256 + threadIdx.x;
    int i = gt >> 2, q = gt & 3;
    if (i >= N_BOX) return;
    const float* p = pred + (size_t)i * PSTRIDE;
    int cbase = q * 20;
    float best = p[5 + cbase];
    int arg = cbase;
    for (int c = 1; c < 20; ++c) {
        float v = p[5 + cbase + c];
        if (v > best) { best = v; arg = cbase + c; }
    }
    for (int d = 1; d < 4; d <<= 1) {
        float ob = __shfl_xor(best, d);
        int   oa = __shfl_xor(arg, d);
        if (ob > best || (ob == best && oa < arg)) { best = ob; arg = oa; }
    }
    if (q == 0) {
        float cx = p[0], cy = p[1], w = p[2], h = p[3], obj = p[4];
        float hw = __fmul_rn(w, 0.5f), hh = __fmul_rn(h, 0.5f);
        float x1 = __fsub_rn(cx, hw), y1 = __fsub_rn(cy, hh);
        float x2 = __fadd_rn(cx, hw), y2 = __fadd_rn(cy, hh);
        bool valid = (obj >= CONF_T);
        float score = valid ? obj : -1.0f;
        keys[i] = fmap_desc(score);
        float4* dr = (float4*)(det + (size_t)i * 8);
        dr[0] = make_float4(x1, y1, x2, y2);
        dr[1] = make_float4(obj, best, (float)arg, 0.0f);
    }
}

// ---- kernel B: rank + scatter, 32-bit keys (ties broken by index). ----
__global__ __launch_bounds__(256) void rank_k(const unsigned* __restrict__ keys,
                                              const float* __restrict__ det,
                                              float4* __restrict__ det_s,
                                              float4* __restrict__ boxes_s,
                                              int* __restrict__ vcount) {
    int t = threadIdx.x;
    int i = blockIdx.x * 32 + (t & 31);
    int s = t >> 5;                    // slice 0..7, 1050 keys each
    unsigned my = (i < N_BOX) ? keys[i] : 0xFFFFFFFFu;
    int cnt = 0, cv = 0;
    int j0 = s * 1050;
    for (int j = j0; j < j0 + 1048; j += 4) {
        uint4 k4 = *(const uint4*)(keys + j);
        cnt += (k4.x < my) + (k4.y < my) + (k4.z < my) + (k4.w < my);
        cnt += (k4.x == my && j     < i) + (k4.y == my && j + 1 < i)
             + (k4.z == my && j + 2 < i) + (k4.w == my && j + 3 < i);
        cv  += ((int)k4.x >= 0) + ((int)k4.y >= 0) + ((int)k4.z >= 0) + ((int)k4.w >= 0);
    }
    {
        unsigned ka = keys[j0 + 1048], kb = keys[j0 + 1049];
        cnt += (ka < my) + (kb < my)
             + (ka == my && j0 + 1048 < i) + (kb == my && j0 + 1049 < i);
        cv  += ((int)ka >= 0) + ((int)kb >= 0);
    }
    __shared__ int sc[256], sv[256];
    sc[t] = cnt; sv[t] = cv;
    __syncthreads();
    if (t < 32) {
        int r = sc[t] + sc[t + 32] + sc[t + 64] + sc[t + 96]
              + sc[t + 128] + sc[t + 160] + sc[t + 192] + sc[t + 224];
        if (i < N_BOX) {
            const float4* dr = (const float4*)(det + (size_t)i * 8);
            float4 b0 = dr[0], b1 = dr[1];
            det_s[(size_t)r * 2]     = b0;
            det_s[(size_t)r * 2 + 1] = b1;
            boxes_s[r] = b0;
        }
        if (blockIdx.x == 0 && t == 0) {
            *vcount = sv[0] + sv[32] + sv[64] + sv[96]
                    + sv[128] + sv[160] + sv[192] + sv[224];
        }
    }
}

// ---- kernel C: suppression bitmask (upper tri, row-major) + transposed
// near-diagonal tiles diagT/sup1/sup2/sup3 (distance 0..3). ----
__global__ __launch_bounds__(64) void mask_k(const float4* __restrict__ boxes_s,
                                             u64* __restrict__ mask,
                                             u64* __restrict__ diagT,
                                             u64* __restrict__ sup1,
                                             u64* __restrict__ sup2,
                                             u64* __restrict__ sup3) {
    int tt = blockIdx.x, lane = threadIdx.x;
    int rb = (int)((2.0f * NW + 1.0f
                    - sqrtf((2.0f * NW + 1.0f) * (2.0f * NW + 1.0f) - 8.0f * (float)tt)) * 0.5f);
    while (rb > 0 && rb * NW - rb * (rb - 1) / 2 > tt) rb--;
    while ((rb + 1) * NW - (rb + 1) * rb / 2 <= tt) rb++;
    int cb = rb + (tt - (rb * NW - rb * (rb - 1) / 2));

    __shared__ float4 cB[64];
    __shared__ float  cA[64];
    int c0 = cb * 64 + lane;
    float4 b = (c0 < N_BOX) ? boxes_s[c0] : make_float4(0.f, 0.f, 0.f, 0.f);
    cB[lane] = b;
    cA[lane] = __fmul_rn(__fsub_rn(b.z, b.x), __fsub_rn(b.w, b.y));
    __syncthreads();
    int r = rb * 64 + lane;
    bool inb = (r < N_BOX);
    float4 rx = boxes_s[inb ? r : (N_BOX - 1)];
    float ra = __fmul_rn(__fsub_rn(rx.z, rx.x), __fsub_rn(rx.w, rx.y));
    u64 bits = 0ull;
    int cbase = cb * 64;
    for (int j = 0; j < 64; ++j) {
        int c = cbase + j;
        if (c >= N_BOX || c <= r) continue;
        float4 cx4 = cB[j];
        float ltx = fmaxf(rx.x, cx4.x), lty = fmaxf(rx.y, cx4.y);
        float rbx = fminf(rx.z, cx4.z), rby = fminf(rx.w, cx4.w);
        float wx = fmaxf(__fsub_rn(rbx, ltx), 0.0f);
        float wy = fmaxf(__fsub_rn(rby, lty), 0.0f);
        float inter = __fmul_rn(wx, wy);
        float denom = __fadd_rn(__fsub_rn(__fadd_rn(ra, cA[j]), inter), 1e-9f);
        float iou = __fdiv_rn(inter, denom);
        if (iou > NMS_T) bits |= (1ull << j);
    }
    if (inb) mask[(size_t)r * NW + cb] = bits;
    int d = cb - rb;
    if (d <= 3) {
        u64 tb = bittranspose64(bits, lane);
        size_t idx = (size_t)cb * 64 + lane;
        if (d == 0)      diagT[idx] = tb;
        else if (d == 1) sup1[idx]  = tb;
        else if (d == 2) sup2[idx]  = tb;
        else             sup3[idx]  = tb;
    }
}

// ---- kernel D: 2-wave producer/consumer scan; pipeline lives in LDS+vmcnt ----
// wave 0 (resolver), phase j: cur = remvW[j] | ballot patches (sup1..3 x A1..3);
//   resolve leaders via diagT ballots; Lbuf[j] (LDS) + keepw[j] (global).
// wave 1 (row DMA), phase j:
//   [j>=2] s_waitcnt vmcnt(17): slot issued at phase j-2 (rows of block j-3)
//   has landed in LDS; ds_read real rows, RMW remvW (lane-owned words).
//   Then extras (>16 leaders, rare, drains before issue), then issue 17
//   unconditional gload_lds for Lbuf[j-1]'s rows (dummy -> zero row).
// Raw s_barrier per phase preserves the vmcnt pipeline.
__global__ __launch_bounds__(128, 1) void scan_k(const u64* __restrict__ mask,
                                                 const u64* __restrict__ diagT,
                                                 const u64* __restrict__ sup1,
                                                 const u64* __restrict__ sup2,
                                                 const u64* __restrict__ sup3,
                                                 const int* __restrict__ vcount,
                                                 u64* __restrict__ keepw) {
    __shared__ __align__(16) u64 rows[2][16][128];   // 2 slots x 16 rows x 1024B
    __shared__ __align__(16) u64 tails[2][128];      // 2 slots x 1024B (16 rows x 2 chunks x 16B)
    __shared__ u64 remvW[NW];
    __shared__ u64 Lbuf[NW];
    int tid = threadIdx.x, lane = tid & 63, wv = tid >> 6;
    int V = *vcount;
    for (int i = tid; i < NW; i += 128) { remvW[i] = 0ull; Lbuf[i] = 0ull; }
    __syncthreads();

    if (wv == 0) {
        // ---------------- wave 0: resolver ----------------
        u64 A1 = 0ull, A2 = 0ull, A3 = 0ull;
        u64 d0P, s1P, s2P, s3P, d0Q, s1Q, s2Q, s3Q;
#define TL(S, kk) do {                                                   \
        int t_ = (kk) < NW ? (kk) : (NW - 1);                            \
        size_t ix_ = (size_t)t_ * 64 + lane;                             \
        d0##S = diagT[ix_]; s1##S = sup1[ix_];                           \
        s2##S = sup2[ix_];  s3##S = sup3[ix_];                           \
    } while (0)
#define STEP0(kk, S) do {                                                \
        int k_ = (kk);                                                   \
        u64 cur_ = remvW[k_];                                            \
        cur_ |= __ballot((s1##S & A1) != 0ull);                          \
        cur_ |= __ballot((s2##S & A2) != 0ull);                          \
        cur_ |= __ballot((s3##S & A3) != 0ull);                          \
        u64 m_ = wmask(k_, V);                                           \
        u64 ns_ = (~cur_) & m_;                                          \
        u64 L_ = 0ull;                                                   \
        while (ns_) {                                                    \
            int b_ = __builtin_ctzll(ns_);                               \
            L_ |= 1ull << b_;                                            \
            u64 sup_ = __ballot((int)((d0##S >> b_) & 1ull));            \
            ns_ &= ~sup_;                                                \
            ns_ &= ~(1ull << b_);                                        \
        }                                                                \
        if (lane == 0) { Lbuf[k_] = L_; keepw[k_] = L_; }                \
        A3 = A2; A2 = A1; A1 = L_;                                       \
        TL(S, k_ + 2);                                                   \
        step_barrier();                                                  \
    } while (0)
        TL(P, 0);
        TL(Q, 1);
        for (int c = 0; c < NW; c += 2) {
            STEP0(c + 0, P);
            STEP0(c + 1, Q);
        }
#undef STEP0
#undef TL
    } else {
        // ---------------- wave 1: LDS-pipelined row DMA ----------------
        for (int j = 0; j < NW; ++j) {
            int slot = j & 1;
            if (j >= 2) {
                asm volatile("s_waitcnt vmcnt(17)" ::: "memory");
                __builtin_amdgcn_sched_barrier(0);
                u64 Lc = Lbuf[j - 3 >= 0 ? j - 3 : 0];
                if (j < 3) Lc = 0ull;
                int nr = __popcll(Lc); nr = nr < 16 ? nr : 16;
                u64 a0 = 0ull, a1 = 0ull, at = 0ull;
                int tix = (lane & 3);
                for (int r = 0; r < nr; ++r) {
                    ulonglong2 v = *(const ulonglong2*)&rows[slot][r][2 * lane];
                    a0 |= v.x; a1 |= v.y;
                    at |= tails[slot][4 * r + 2 * (tix >> 1) + (tix & 1)];
                }
                remvW[2 * lane]     |= a0;
                remvW[2 * lane + 1] |= a1;
                if (lane < 4) remvW[128 + lane] |= at;
                // drain our ds_reads before gload_lds re-fills this slot
                asm volatile("s_waitcnt lgkmcnt(0)" ::: "memory");
                __builtin_amdgcn_sched_barrier(0);
            }
            u64 Lp = (j >= 1) ? Lbuf[j - 1] : 0ull;
            int rbase = (j - 1) << 6;
            int cntL = __popcll(Lp);
            // ---- extras (>16 leaders; first blocks only) BEFORE slot issue ----
            if (cntL > 16) {
                u64 rem = Lp;
                for (int s = 0; s < 16; ++s) rem &= rem - 1ull;
                int tw = (lane < 4) ? (128 + lane) : 131;
                u64 xa = 0ull, xb = 0ull, xc = 0ull;
                while (rem) {
                    size_t ri = (size_t)(rbase + __builtin_ctzll(rem));
                    rem &= rem - 1ull;
                    const u64* rp = mask + ri * NW;
                    ulonglong2 v = *(const ulonglong2*)(rp + 2 * lane);
                    xa |= v.x; xb |= v.y; xc |= rp[tw];
                }
                remvW[2 * lane]     |= xa;
                remvW[2 * lane + 1] |= xb;
                if (lane < 4) remvW[128 + lane] |= xc;
            }
            // ---- issue 16 row-DMAs + 1 tails-DMA (all unconditional) ----
            {
                u64 rem = Lp;
                int i0, i1, i2, i3, i4, i5, i6, i7, i8, i9, i10, i11, i12, i13, i14, i15;
#define NXT(dst) do { dst = rem ? (rbase + __builtin_ctzll(rem)) : ZROWI;  \
                      rem &= rem - 1ull; } while (0)
                NXT(i0); NXT(i1); NXT(i2); NXT(i3);
                NXT(i4); NXT(i5); NXT(i6); NXT(i7);
                NXT(i8); NXT(i9); NXT(i10); NXT(i11);
                NXT(i12); NXT(i13); NXT(i14); NXT(i15);
#undef NXT
#define GL(rr, ii) gload16(mask + (size_t)(ii) * NW + 2 * lane, &rows[slot][rr][0])
                GL(0, i0);  GL(1, i1);  GL(2, i2);  GL(3, i3);
                GL(4, i4);  GL(5, i5);  GL(6, i6);  GL(7, i7);
                GL(8, i8);  GL(9, i9);  GL(10, i10); GL(11, i11);
                GL(12, i12); GL(13, i13); GL(14, i14); GL(15, i15);
#undef GL
                // tails: lane<32 covers (row = lane>>1, chunk = lane&1)
                int rsel = lane >> 1;
                int ri = (rsel < cntL && rsel < 16) ? (rbase + selbit(Lp, rsel)) : ZROWI;
                const u64* tsrc = mask + (size_t)ri * NW + 128 + 2 * (lane & 1);
                gload16(tsrc, &tails[slot][0]);
            }
            step_barrier();
        }
    }
}

// ---- kernel E: masked write-out (7 cols) ----
__global__ __launch_bounds__(256) void out_k(const float* __restrict__ det_s,
                                             const u64* __restrict__ keepw,
                                             float* __restrict__ out) {
    int e = blockIdx.x * 256 + threadIdx.x;
    if (e >= N_BOX * 7) return;
    int r = e / 7, c = e - r * 7;
    bool k = (keepw[r >> 6] >> (r & 63)) & 1ull;
    out[e] = k ? det_s[r * 8 + c] : 0.0f;
}

extern "C" void kernel_launch(void* const* d_in, const int* in_sizes, int n_in,
                              void* d_out, int out_size, void* d_ws, size_t ws_size,
                              hipStream_t stream) {
    const float* pred = (const float*)d_in[0];
    char* ws = (char*)d_ws;
    float*    det     = (float*)   (ws + OFF_DET);
    u64*      diagT   = (u64*)     (ws + OFF_DIAGT);
    u64*      sup1    = (u64*)     (ws + OFF_SUP1);
    u64*      sup2    = (u64*)     (ws + OFF_SUP2);
    u64*      sup3    = (u64*)     (ws + OFF_SUP3);
    unsigned* keys    = (unsigned*)(ws + OFF_KEYS);
    float*    det_s   = (float*)   (ws + OFF_DETS);
    float4*   boxes_s = (float4*)  (ws + OFF_BOXESS);
    u64*      mask    = (u64*)     (ws + OFF_MASK);
    u64*      keepw   = (u64*)     (ws + OFF_KEEPW);
    int*      vcount  = (int*)     (ws + OFF_VCNT);

    prep_k<<<132, 256, 0, stream>>>(pred, det, keys, mask);
    rank_k<<<264, 256, 0, stream>>>(keys, det, (float4*)det_s, boxes_s, vcount);
    mask_k<<<NTILE, 64, 0, stream>>>(boxes_s, mask, diagT, sup1, sup2, sup3);
    scan_k<<<1, 128, 0, stream>>>(mask, diagT, sup1, sup2, sup3, vcount, keepw);
    out_k <<<(N_BOX * 7 + 255) / 256, 256, 0, stream>>>(det_s, keepw, (float*)d_out);
}

// Round 13
// 154.976 us; speedup vs baseline: 1.5357x; 1.5357x over previous
//
#include <hip/hip_runtime.h>
#include <stdint.h>

#define N_BOX 8400
#define NCLS 80
#define PSTRIDE 85
#define NW 132            // 64-box blocks covering 8400
#define NTILE 8778        // NW*(NW+1)/2 upper-tri tiles
#define ZROWI N_BOX       // mask row 8400 = all zeros (dummy row target)
#define CONF_T 0.01f
#define NMS_T 0.2f

typedef unsigned long long u64;

// ws layout (bytes). diagT/sup1/sup2/sup3 ALIAS det+keys: both dead after
// rank_k; tiles written by mask_k (later in-stream) — lifetimes disjoint.
#define OFF_DET     0                    // 8400 x 8 f32   = 268800
#define OFF_DIAGT   0                    // 132*64 u64     = 67584  (alias)
#define OFF_SUP1    67584                // 132*64 u64     = 67584  (alias)
#define OFF_SUP2    135168               // 132*64 u64     = 67584  (alias)
#define OFF_SUP3    202752               // 132*64 u64     = 67584  (alias, tail overlaps keys — keys dead then)
#define OFF_KEYS    268800               // 8400 u32       = 33600
#define OFF_DETS    336000               // 8400 x 8 f32   = 268800
#define OFF_BOXESS  604800               // 8400 float4    = 134400
#define OFF_MASK    739200               // 8401 x 132 u64 = 8871456 (row 8400 = zeros)
#define OFF_KEEPW   9610656              // 132 u64        = 1056
#define OFF_VCNT    9611712              // 1 int

__device__ __forceinline__ unsigned fmap_desc(float f) {
    unsigned u = __float_as_uint(f);
    unsigned m = (u & 0x80000000u) ? ~u : (u | 0x80000000u); // monotone ascending
    return ~m;                                               // descending
}

__device__ __forceinline__ u64 readlane64(u64 v, int lane) {
    unsigned lo = (unsigned)__builtin_amdgcn_readlane((int)(unsigned)v, lane);
    unsigned hi = (unsigned)__builtin_amdgcn_readlane((int)(unsigned)(v >> 32), lane);
    return ((u64)hi << 32) | lo;
}

__device__ __forceinline__ u64 shfl_xor64(u64 v, int m) {
    int lo = __shfl_xor((int)(unsigned)v, m);
    int hi = __shfl_xor((int)(unsigned)(v >> 32), m);
    return ((u64)(unsigned)hi << 32) | (unsigned)lo;
}

// 64x64 bit-matrix transpose across lanes. Verified R8-R12 (absmax 0).
__device__ __forceinline__ u64 bittranspose64(u64 x, int lane) {
    const u64 P0 = 0x5555555555555555ull, P1 = 0x3333333333333333ull,
              P2 = 0x0F0F0F0F0F0F0F0Full, P3 = 0x00FF00FF00FF00FFull,
              P4 = 0x0000FFFF0000FFFFull, P5 = 0x00000000FFFFFFFFull;
#define TSTEP(s, p) do {                                                 \
        u64 y = shfl_xor64(x, s);                                        \
        x = (lane & (s)) ? ((x & ~(p)) | ((y & ~(p)) >> (s)))            \
                         : ((x & (p))  | ((y & (p))  << (s)));           \
    } while (0)
    TSTEP(1, P0); TSTEP(2, P1); TSTEP(4, P2);
    TSTEP(8, P3); TSTEP(16, P4); TSTEP(32, P5);
#undef TSTEP
    return x;
}

__device__ __forceinline__ u64 wmask(int w, int V) {
    int nb = V - (w << 6);
    if (nb <= 0) return 0ull;
    if (nb >= 64) return ~0ull;
    return (1ull << nb) - 1ull;
}

// Raw barrier: LDS drained, vmcnt pipeline PRESERVED (no __syncthreads drain).
__device__ __forceinline__ void step_barrier() {
    asm volatile("s_waitcnt lgkmcnt(0)" ::: "memory");
    __builtin_amdgcn_s_barrier();
    asm volatile("" ::: "memory");
}

// ---- kernel A: per-row preprocess, 4 lanes per row; zeroes mask row 8400 ----
__global__ __launch_bounds__(256) void prep_k(const float* __restrict__ pred,
                                              float* __restrict__ det,
                                              unsigned* __restrict__ keys,
                                              u64* __restrict__ mask) {
    if (blockIdx.x == 0 && threadIdx.x < NW)
        mask[(size_t)ZROWI * NW + threadIdx.x] = 0ull;
    int gt = blockIdx.x * 256 + threadIdx.x;
    int i = gt >> 2, q = gt & 3;
    if (i >= N_BOX) return;
    const float* p = pred + (size_t)i * PSTRIDE;
    int cbase = q * 20;
    float best = p[5 + cbase];
    int arg = cbase;
    for (int c = 1; c < 20; ++c) {
        float v = p[5 + cbase + c];
        if (v > best) { best = v; arg = cbase + c; }
    }
    for (int d = 1; d < 4; d <<= 1) {
        float ob = __shfl_xor(best, d);
        int   oa = __shfl_xor(arg, d);
        if (ob > best || (ob == best && oa < arg)) { best = ob; arg = oa; }
    }
    if (q == 0) {
        float cx = p[0], cy = p[1], w = p[2], h = p[3], obj = p[4];
        float hw = __fmul_rn(w, 0.5f), hh = __fmul_rn(h, 0.5f);
        float x1 = __fsub_rn(cx, hw), y1 = __fsub_rn(cy, hh);
        float x2 = __fadd_rn(cx, hw), y2 = __fadd_rn(cy, hh);
        bool valid = (obj >= CONF_T);
        float score = valid ? obj : -1.0f;
        keys[i] = fmap_desc(score);
        float4* dr = (float4*)(det + (size_t)i * 8);
        dr[0] = make_float4(x1, y1, x2, y2);
        dr[1] = make_float4(obj, best, (float)arg, 0.0f);
    }
}

// ---- kernel B: rank + scatter, u32 keys, 16B-ALIGNED slices (1056/1008). ----
// Ties broken by index (key equal -> smaller original index ranks first).
__global__ __launch_bounds__(256) void rank_k(const unsigned* __restrict__ keys,
                                              const float* __restrict__ det,
                                              float4* __restrict__ det_s,
                                              float4* __restrict__ boxes_s,
                                              int* __restrict__ vcount) {
    int t = threadIdx.x;
    int i = blockIdx.x * 32 + (t & 31);
    int s = t >> 5;                    // slice 0..7: 7x1056 + 1x1008 = 8400
    unsigned my = (i < N_BOX) ? keys[i] : 0xFFFFFFFFu;
    int cnt = 0, cv = 0;
    int j0 = s * 1056;                 // 1056*4B = 4224B, 16B aligned
    int jend = (s == 7) ? N_BOX : (j0 + 1056);
    for (int j = j0; j < jend; j += 4) {
        uint4 k4 = *(const uint4*)(keys + j);
        cnt += (k4.x < my) + (k4.y < my) + (k4.z < my) + (k4.w < my);
        cnt += (k4.x == my && j     < i) + (k4.y == my && j + 1 < i)
             + (k4.z == my && j + 2 < i) + (k4.w == my && j + 3 < i);
        cv  += ((int)k4.x >= 0) + ((int)k4.y >= 0) + ((int)k4.z >= 0) + ((int)k4.w >= 0);
    }
    __shared__ int sc[256], sv[256];
    sc[t] = cnt; sv[t] = cv;
    __syncthreads();
    if (t < 32) {
        int r = sc[t] + sc[t + 32] + sc[t + 64] + sc[t + 96]
              + sc[t + 128] + sc[t + 160] + sc[t + 192] + sc[t + 224];
        if (i < N_BOX) {
            const float4* dr = (const float4*)(det + (size_t)i * 8);
            float4 b0 = dr[0], b1 = dr[1];
            det_s[(size_t)r * 2]     = b0;
            det_s[(size_t)r * 2 + 1] = b1;
            boxes_s[r] = b0;
        }
        if (blockIdx.x == 0 && t == 0) {
            *vcount = sv[0] + sv[32] + sv[64] + sv[96]
                    + sv[128] + sv[160] + sv[192] + sv[224];
        }
    }
}

// ---- kernel C: suppression bitmask (upper tri, row-major) + transposed
// near-diagonal tiles diagT/sup1/sup2/sup3 (distance 0..3). ----
__global__ __launch_bounds__(64) void mask_k(const float4* __restrict__ boxes_s,
                                             u64* __restrict__ mask,
                                             u64* __restrict__ diagT,
                                             u64* __restrict__ sup1,
                                             u64* __restrict__ sup2,
                                             u64* __restrict__ sup3) {
    int tt = blockIdx.x, lane = threadIdx.x;
    int rb = (int)((2.0f * NW + 1.0f
                    - sqrtf((2.0f * NW + 1.0f) * (2.0f * NW + 1.0f) - 8.0f * (float)tt)) * 0.5f);
    while (rb > 0 && rb * NW - rb * (rb - 1) / 2 > tt) rb--;
    while ((rb + 1) * NW - (rb + 1) * rb / 2 <= tt) rb++;
    int cb = rb + (tt - (rb * NW - rb * (rb - 1) / 2));

    __shared__ float4 cB[64];
    __shared__ float  cA[64];
    int c0 = cb * 64 + lane;
    float4 b = (c0 < N_BOX) ? boxes_s[c0] : make_float4(0.f, 0.f, 0.f, 0.f);
    cB[lane] = b;
    cA[lane] = __fmul_rn(__fsub_rn(b.z, b.x), __fsub_rn(b.w, b.y));
    __syncthreads();
    int r = rb * 64 + lane;
    bool inb = (r < N_BOX);
    float4 rx = boxes_s[inb ? r : (N_BOX - 1)];
    float ra = __fmul_rn(__fsub_rn(rx.z, rx.x), __fsub_rn(rx.w, rx.y));
    u64 bits = 0ull;
    int cbase = cb * 64;
    for (int j = 0; j < 64; ++j) {
        int c = cbase + j;
        if (c >= N_BOX || c <= r) continue;
        float4 cx4 = cB[j];
        float ltx = fmaxf(rx.x, cx4.x), lty = fmaxf(rx.y, cx4.y);
        float rbx = fminf(rx.z, cx4.z), rby = fminf(rx.w, cx4.w);
        float wx = fmaxf(__fsub_rn(rbx, ltx), 0.0f);
        float wy = fmaxf(__fsub_rn(rby, lty), 0.0f);
        float inter = __fmul_rn(wx, wy);
        float denom = __fadd_rn(__fsub_rn(__fadd_rn(ra, cA[j]), inter), 1e-9f);
        float iou = __fdiv_rn(inter, denom);
        if (iou > NMS_T) bits |= (1ull << j);
    }
    if (inb) mask[(size_t)r * NW + cb] = bits;
    int d = cb - rb;
    if (d <= 3) {
        u64 tb = bittranspose64(bits, lane);
        size_t idx = (size_t)cb * 64 + lane;
        if (d == 0)      diagT[idx] = tb;
        else if (d == 1) sup1[idx]  = tb;
        else if (d == 2) sup2[idx]  = tb;
        else             sup3[idx]  = tb;
    }
}

// ---- kernel D: 3-wave producer/consumer greedy scan ----
// wave 0 (resolver), phase k: cur = remvP1[k]|remvP2[k] | ballot patches
//   (sup1..3 x A1..3); resolve leaders via diagT ballots; Lbuf[k] + keepw[k].
// waves 1,2 (row-OR, split by leader-word half: wave1 = bits 0..31,
//   wave2 = bits 32..63), phase j:
//   consume own 4-slot set issued at phase j-2 (rows of block j-3) into reg
//   remv; publish own remvP[j+1] (covers rows <= j-3 — meets wave0's k-4
//   deadline; sup1..3 patch distances 1..3); read Lbuf[j-1], issue own <=4
//   slot loads (dummy -> zero row 8400); extras (>4 in own half) drain
//   immediately in 8-row batches.
// Raw s_barrier per phase preserves each wave's vmcnt pipeline.
__global__ __launch_bounds__(192, 1) void scan_k(const u64* __restrict__ mask,
                                                 const u64* __restrict__ diagT,
                                                 const u64* __restrict__ sup1,
                                                 const u64* __restrict__ sup2,
                                                 const u64* __restrict__ sup3,
                                                 const int* __restrict__ vcount,
                                                 u64* __restrict__ keepw) {
    __shared__ u64 remvP1[NW + 2];
    __shared__ u64 remvP2[NW + 2];
    __shared__ u64 Lbuf[NW];
    int tid = threadIdx.x, lane = tid & 63, wv = tid >> 6;
    int V = *vcount;
    for (int i = tid; i < NW + 2; i += 192) { remvP1[i] = 0ull; remvP2[i] = 0ull; }
    __syncthreads();

    if (wv == 0) {
        // ---------------- wave 0: resolver ----------------
        u64 A1 = 0ull, A2 = 0ull, A3 = 0ull;
        u64 d0P, s1P, s2P, s3P, d0Q, s1Q, s2Q, s3Q;
#define TL(S, kk) do {                                                   \
        int t_ = (kk) < NW ? (kk) : (NW - 1);                            \
        size_t ix_ = (size_t)t_ * 64 + lane;                             \
        d0##S = diagT[ix_]; s1##S = sup1[ix_];                           \
        s2##S = sup2[ix_];  s3##S = sup3[ix_];                           \
    } while (0)
#define STEP0(kk, S) do {                                                \
        int k_ = (kk);                                                   \
        u64 cur_ = remvP1[k_] | remvP2[k_];                              \
        cur_ |= __ballot((s1##S & A1) != 0ull);                          \
        cur_ |= __ballot((s2##S & A2) != 0ull);                          \
        cur_ |= __ballot((s3##S & A3) != 0ull);                          \
        u64 m_ = wmask(k_, V);                                           \
        u64 ns_ = (~cur_) & m_;                                          \
        u64 L_ = 0ull;                                                   \
        while (ns_) {                                                    \
            int b_ = __builtin_ctzll(ns_);                               \
            L_ |= 1ull << b_;                                            \
            u64 sup_ = __ballot((int)((d0##S >> b_) & 1ull));            \
            ns_ &= ~sup_;                                                \
            ns_ &= ~(1ull << b_);                                        \
        }                                                                \
        if (lane == 0) { Lbuf[k_] = L_; keepw[k_] = L_; }                \
        A3 = A2; A2 = A1; A1 = L_;                                       \
        TL(S, k_ + 2);                                                   \
        step_barrier();                                                  \
    } while (0)
        TL(P, 0);
        TL(Q, 1);
        for (int c = 0; c < NW; c += 2) {
            STEP0(c + 0, P);
            STEP0(c + 1, Q);
        }
#undef STEP0
#undef TL
    } else {
        // ---------------- waves 1,2: row-OR, split by half-word ----------------
        int half = wv - 1;                     // 0: leader bits 0..31, 1: 32..63
        u64* myP = half ? remvP2 : remvP1;
        int tw = (lane < 4) ? (128 + lane) : 131;
        u64 Ra = 0ull, Rb = 0ull, Rc = 0ull;   // this wave's partial remv
        u64 Pa0=0,Pa1=0,Pa2=0,Pa3=0, Pb0=0,Pb1=0,Pb2=0,Pb3=0, Pc0=0,Pc1=0,Pc2=0,Pc3=0;
        u64 Qa0=0,Qa1=0,Qa2=0,Qa3=0, Qb0=0,Qb1=0,Qb2=0,Qb3=0, Qc0=0,Qc1=0,Qc2=0,Qc3=0;

#define CONS(S) do {                                                     \
        Ra |= (S##a0 | S##a1) | (S##a2 | S##a3);                         \
        Rb |= (S##b0 | S##b1) | (S##b2 | S##b3);                         \
        Rc |= (S##c0 | S##c1) | (S##c2 | S##c3);                         \
    } while (0)

#define LROW(S, i) do {                                                  \
        size_t ri_ = rem_ ? (size_t)(rbase_ + __builtin_ctz(rem_))       \
                          : (size_t)ZROWI;                               \
        rem_ &= rem_ - 1u;                                               \
        const u64* rp_ = mask + ri_ * NW;                                \
        ulonglong2 v_ = *(const ulonglong2*)(rp_ + 2 * lane);            \
        S##a##i = v_.x; S##b##i = v_.y; S##c##i = rp_[tw];               \
    } while (0)

#define STEP1(jj, S) do {                                                \
        int j_ = (jj);                                                   \
        CONS(S);                               /* rows of block j-3 */   \
        int w_ = j_ + 1;                                                 \
        u64 rw_ = (w_ < 128) ? ((w_ & 1) ? Rb : Ra) : Rc;                \
        int sl_ = (w_ < 128) ? (w_ >> 1) : (w_ - 128);                   \
        u64 pv_ = readlane64(rw_, sl_);                                  \
        if (lane == 0) myP[w_] = pv_;                                    \
        u64 Lfull_ = (j_ >= 1) ? Lbuf[j_ - 1] : 0ull;                    \
        unsigned rem_ = half ? (unsigned)(Lfull_ >> 32)                  \
                             : (unsigned)Lfull_;                         \
        int rbase_ = ((j_ - 1) << 6) + 32 * half;                        \
        LROW(S, 0); LROW(S, 1); LROW(S, 2); LROW(S, 3);                  \
        while (rem_) {                          /* extras: 8/batch */    \
            u64 xa_ = 0, xb_ = 0, xc_ = 0;                               \
            for (int q_ = 0; q_ < 8; ++q_) {                             \
                size_t ri_ = rem_ ? (size_t)(rbase_ + __builtin_ctz(rem_)) \
                                  : (size_t)ZROWI;                       \
                rem_ &= rem_ - 1u;                                       \
                const u64* rp_ = mask + ri_ * NW;                        \
                ulonglong2 v_ = *(const ulonglong2*)(rp_ + 2 * lane);    \
                xa_ |= v_.x; xb_ |= v_.y; xc_ |= rp_[tw];                \
            }                                                            \
            Ra |= xa_; Rb |= xb_; Rc |= xc_;                             \
        }                                                                \
        step_barrier();                                                  \
    } while (0)

        for (int c = 0; c < NW; c += 2) {
            STEP1(c + 0, P);
            STEP1(c + 1, Q);
        }
#undef STEP1
#undef LROW
#undef CONS
    }
}

// ---- kernel E: masked write-out (7 cols) ----
__global__ __launch_bounds__(256) void out_k(const float* __restrict__ det_s,
                                             const u64* __restrict__ keepw,
                                             float* __restrict__ out) {
    int e = blockIdx.x * 256 + threadIdx.x;
    if (e >= N_BOX * 7) return;
    int r = e / 7, c = e - r * 7;
    bool k = (keepw[r >> 6] >> (r & 63)) & 1ull;
    out[e] = k ? det_s[r * 8 + c] : 0.0f;
}

extern "C" void kernel_launch(void* const* d_in, const int* in_sizes, int n_in,
                              void* d_out, int out_size, void* d_ws, size_t ws_size,
                              hipStream_t stream) {
    const float* pred = (const float*)d_in[0];
    char* ws = (char*)d_ws;
    float*    det     = (float*)   (ws + OFF_DET);
    u64*      diagT   = (u64*)     (ws + OFF_DIAGT);
    u64*      sup1    = (u64*)     (ws + OFF_SUP1);
    u64*      sup2    = (u64*)     (ws + OFF_SUP2);
    u64*      sup3    = (u64*)     (ws + OFF_SUP3);
    unsigned* keys    = (unsigned*)(ws + OFF_KEYS);
    float*    det_s   = (float*)   (ws + OFF_DETS);
    float4*   boxes_s = (float4*)  (ws + OFF_BOXESS);
    u64*      mask    = (u64*)     (ws + OFF_MASK);
    u64*      keepw   = (u64*)     (ws + OFF_KEEPW);
    int*      vcount  = (int*)     (ws + OFF_VCNT);

    prep_k<<<132, 256, 0, stream>>>(pred, det, keys, mask);
    rank_k<<<264, 256, 0, stream>>>(keys, det, (float4*)det_s, boxes_s, vcount);
    mask_k<<<NTILE, 64, 0, stream>>>(boxes_s, mask, diagT, sup1, sup2, sup3);
    scan_k<<<1, 192, 0, stream>>>(mask, diagT, sup1, sup2, sup3, vcount, keepw);
    out_k <<<(N_BOX * 7 + 255) / 256, 256, 0, stream>>>(det_s, keepw, (float*)d_out);
}